// Round 1
// baseline (607.898 us; speedup 1.0000x reference)
//
#include <hip/hip_runtime.h>
#include <hip/hip_bf16.h>

// ---------------------------------------------------------------------------
// Bahdanau attention, fused.  B=64, S=2048, E=D=U=512.
//  K1: pack W1 (fp32) -> bf16 in MFMA B-fragment order (ws)
//  K2: c[b,u] = H@W2 + b1 + b2   (fp32, ws)
//  K3: scores[b,s] = tanh(EO@W1 + c)·V + bv   (bf16 MFMA, fused epilogue)
//  K4: softmax over S (in-place in d_out weights region)
//  K5: context[b,e] = sum_s w[b,s]*EO[b,s,e]  (atomics into zeroed d_out)
// d_out layout: context [64*512] then weights [64*2048].
// ---------------------------------------------------------------------------

typedef __attribute__((ext_vector_type(8))) short bf16x8;   // 8 bf16 = 4 VGPR
typedef __attribute__((ext_vector_type(4))) short bf16x4;   // 4 bf16 = 8B
typedef __attribute__((ext_vector_type(4))) float f32x4;

#define NB 64
#define NS 2048
#define NE 512
#define NU 512

__device__ __forceinline__ unsigned short f2bf(float f) {
  union { float f; unsigned int u; } x; x.f = f;
  unsigned int u = x.u;
  unsigned int r = (u + 0x7fffu + ((u >> 16) & 1u)) >> 16;  // RNE
  return (unsigned short)r;
}

__device__ __forceinline__ float tanh_fast(float x) {
  // tanh(x) = 1 - 2/(e^{2x}+1); clamp keeps e^{2x} finite (values are ~N(0,1.3))
  x = fminf(fmaxf(x, -15.f), 15.f);
  float e = __expf(2.f * x);
  return 1.f - 2.f / (e + 1.f);
}

// --- K1: pack W1[k][n] (fp32, row-major 512x512) into bf16 MFMA B-frag order:
//     W1p[(((nt*16+kt)*64 + lane)*8 + j)] = bf16(W1[kt*32+(lane>>4)*8+j][nt*16+(lane&15)])
__global__ __launch_bounds__(256) void pack_w1_kernel(
    const float* __restrict__ W1, unsigned short* __restrict__ W1p) {
  int t = blockIdx.x * 256 + threadIdx.x;     // 0..262143, coalesced read
  int k = t >> 9, n = t & 511;
  int kt = k >> 5, kr = k & 31;
  int quad = kr >> 3, j = kr & 7;
  int l = (quad << 4) | (n & 15);
  int nt = n >> 4;
  int dst = ((((nt << 4) + kt) * 64 + l) << 3) + j;
  W1p[dst] = f2bf(W1[t]);
}

// --- K2: c[b][u] = sum_d H[b][d]*W2[d][u] + b1[u] + b2[u]
__global__ __launch_bounds__(512) void compute_c_kernel(
    const float* __restrict__ H, const float* __restrict__ W2,
    const float* __restrict__ b1, const float* __restrict__ b2,
    float* __restrict__ cvec) {
  const int b = blockIdx.x, u = threadIdx.x;
  __shared__ float hs[512];
  hs[u] = H[(b << 9) + u];
  __syncthreads();
  float s = 0.f;
#pragma unroll 8
  for (int d = 0; d < 512; d++) s = fmaf(hs[d], W2[(d << 9) + u], s);
  cvec[(b << 9) + u] = s + b1[u] + b2[u];
}

// --- K3: scores.  grid 1024 (= 64 b * 16 s-strips), 256 thr (4 waves).
// Block: 128 rows of EO (one b).  Wave: 32 rows (two 16-row MFMA tiles).
// EO staged fp32->bf16 in LDS in two K=256 halves; A-frags live in 128 VGPRs.
// B-frags: one coalesced 16B global load each from packed W1p (L2-resident).
__global__ __launch_bounds__(256, 2) void scores_kernel(
    const float* __restrict__ EO, const unsigned short* __restrict__ W1p,
    const float* __restrict__ cvec, const float* __restrict__ V,
    const float* __restrict__ bv, float* __restrict__ scores) {
  // 264 = 256 + 8 pad: row stride 132 dwords -> start-bank shift 4/row,
  // ds_read_b128 spreads uniformly over all 32 banks (min phases, no conflict)
  __shared__ unsigned short As[128 * 264];
  __shared__ float cs[512];
  __shared__ float vs[512];

  const int tid = threadIdx.x;
  const int bx = blockIdx.x;
  const int b = bx >> 4;
  const int s0 = (bx & 15) << 7;   // *128

  cs[tid] = cvec[(b << 9) + tid];
  cs[tid + 256] = cvec[(b << 9) + 256 + tid];
  vs[tid] = V[tid];
  vs[tid + 256] = V[256 + tid];

  const int lane = tid & 63, wave = tid >> 6;
  const int quad = lane >> 4, col = lane & 15;

  const float* eo_base = EO + ((size_t)(b * NS + s0)) * NE;

  bf16x8 afrag[2][16];   // [row-tile][ktile] : 128 VGPRs

  for (int ph = 0; ph < 2; ph++) {
    if (ph) __syncthreads();           // afrag loads of phase 0 done
    // stage 128 rows x 256 k (fp32 -> bf16).  Each wave copies exactly one
    // contiguous 1KB row-half per iteration -> perfectly coalesced.
#pragma unroll
    for (int it = 0; it < 32; it++) {
      int idx = (it * 256 + tid) * 4;       // 0..32767
      int row = idx >> 8;
      int c = idx & 255;
      const float4* src =
          reinterpret_cast<const float4*>(eo_base + (size_t)row * NE + ph * 256 + c);
      float4 f = *src;
      bf16x4 h;
      h.x = (short)f2bf(f.x); h.y = (short)f2bf(f.y);
      h.z = (short)f2bf(f.z); h.w = (short)f2bf(f.w);
      *reinterpret_cast<bf16x4*>(&As[row * 264 + c]) = h;
    }
    __syncthreads();
    // A-fragment loads for this K-half: A[m=lane&15][k=quad*8+j]
#pragma unroll
    for (int kk = 0; kk < 8; kk++) {
      int koff = kk * 32 + quad * 8;
      afrag[0][ph * 8 + kk] =
          *reinterpret_cast<const bf16x8*>(&As[(wave * 32 + col) * 264 + koff]);
      afrag[1][ph * 8 + kk] =
          *reinterpret_cast<const bf16x8*>(&As[(wave * 32 + 16 + col) * 264 + koff]);
    }
  }

  float sacc[2][4] = {{0.f, 0.f, 0.f, 0.f}, {0.f, 0.f, 0.f, 0.f}};
  const bf16x8* Wp = reinterpret_cast<const bf16x8*>(W1p);
  const float bvv = bv[0];

  for (int nt = 0; nt < 32; nt++) {
    f32x4 acc0 = {0.f, 0.f, 0.f, 0.f};
    f32x4 acc1 = {0.f, 0.f, 0.f, 0.f};
    const bf16x8* p = Wp + nt * 1024 + lane;   // (nt*16+kt)*64 + lane
#pragma unroll
    for (int kt = 0; kt < 16; kt++) {
      bf16x8 bfr = p[kt * 64];
      acc0 = __builtin_amdgcn_mfma_f32_16x16x32_bf16(afrag[0][kt], bfr, acc0, 0, 0, 0);
      acc1 = __builtin_amdgcn_mfma_f32_16x16x32_bf16(afrag[1][kt], bfr, acc1, 0, 0, 0);
    }
    // fused epilogue: score partial += tanh(acc + c[u]) * V[u]
    int u = (nt << 4) + col;
    float cu = cs[u], vu = vs[u];
#pragma unroll
    for (int r = 0; r < 4; r++) {
      sacc[0][r] += tanh_fast(acc0[r] + cu) * vu;
      sacc[1][r] += tanh_fast(acc1[r] + cu) * vu;
    }
  }

  // reduce over the 16 columns held by each quad-group (masks < 16 stay in group)
#pragma unroll
  for (int m = 1; m < 16; m <<= 1) {
#pragma unroll
    for (int t = 0; t < 2; t++)
#pragma unroll
      for (int r = 0; r < 4; r++)
        sacc[t][r] += __shfl_xor(sacc[t][r], m, 64);
  }
  if (col == 0) {
#pragma unroll
    for (int t = 0; t < 2; t++)
#pragma unroll
      for (int r = 0; r < 4; r++)
        scores[(size_t)b * NS + s0 + wave * 32 + t * 16 + quad * 4 + r] =
            sacc[t][r] + bvv;
  }
}

// --- K4: softmax over S, in place.  64 blocks x 256 thr, 8 elems/thread.
__global__ __launch_bounds__(256) void softmax_kernel(float* __restrict__ w) {
  const int b = blockIdx.x, tid = threadIdx.x;
  float* row = w + (size_t)b * NS;
  float v[8];
  float mx = -1e30f;
#pragma unroll
  for (int i = 0; i < 8; i++) { v[i] = row[i * 256 + tid]; mx = fmaxf(mx, v[i]); }
#pragma unroll
  for (int off = 32; off; off >>= 1) mx = fmaxf(mx, __shfl_xor(mx, off, 64));
  __shared__ float redm[4], reds[4];
  const int wv = tid >> 6, ln = tid & 63;
  if (ln == 0) redm[wv] = mx;
  __syncthreads();
  mx = fmaxf(fmaxf(redm[0], redm[1]), fmaxf(redm[2], redm[3]));
  float s = 0.f;
#pragma unroll
  for (int i = 0; i < 8; i++) { v[i] = __expf(v[i] - mx); s += v[i]; }
#pragma unroll
  for (int off = 32; off; off >>= 1) s += __shfl_xor(s, off, 64);
  if (ln == 0) reds[wv] = s;
  __syncthreads();
  s = reds[0] + reds[1] + reds[2] + reds[3];
  float inv = 1.f / s;
#pragma unroll
  for (int i = 0; i < 8; i++) row[i * 256 + tid] = v[i] * inv;
}

// --- K5: context[b][e] = sum_s w[b][s]*EO[b][s][e].  grid (64,8), 256 thr.
__global__ __launch_bounds__(256) void context_kernel(
    const float* __restrict__ EO, const float* __restrict__ w,
    float* __restrict__ ctx) {
  const int b = blockIdx.x, sc = blockIdx.y, tid = threadIdx.x;
  __shared__ float wl[256];
  wl[tid] = w[(size_t)b * NS + sc * 256 + tid];
  __syncthreads();
  const float2* eo2 =
      reinterpret_cast<const float2*>(EO + ((size_t)b * NS + sc * 256) * NE) + tid;
  float ax = 0.f, ay = 0.f;
#pragma unroll 8
  for (int i = 0; i < 256; i++) {
    float2 e = eo2[(size_t)i * 256];
    float wt = wl[i];
    ax = fmaf(wt, e.x, ax);
    ay = fmaf(wt, e.y, ay);
  }
  atomicAdd(&ctx[(b << 9) + tid * 2], ax);
  atomicAdd(&ctx[(b << 9) + tid * 2 + 1], ay);
}

extern "C" void kernel_launch(void* const* d_in, const int* in_sizes, int n_in,
                              void* d_out, int out_size, void* d_ws, size_t ws_size,
                              hipStream_t stream) {
  (void)in_sizes; (void)n_in; (void)out_size; (void)ws_size;
  const float* H  = (const float*)d_in[0];
  const float* EO = (const float*)d_in[1];
  const float* W1 = (const float*)d_in[2];
  const float* b1 = (const float*)d_in[3];
  const float* W2 = (const float*)d_in[4];
  const float* b2 = (const float*)d_in[5];
  const float* V  = (const float*)d_in[6];
  const float* bv = (const float*)d_in[7];

  float* out_ctx = (float*)d_out;                       // [64*512]
  float* out_w   = (float*)d_out + NB * NE;             // [64*2048] (scores->weights)

  unsigned short* W1p = (unsigned short*)d_ws;          // 512 KB
  float* cvec = (float*)((char*)d_ws + 512 * 1024);     // 128 KB

  hipMemsetAsync(out_ctx, 0, (size_t)NB * NE * sizeof(float), stream);
  pack_w1_kernel<<<1024, 256, 0, stream>>>(W1, W1p);
  compute_c_kernel<<<NB, 512, 0, stream>>>(H, W2, b1, b2, cvec);
  scores_kernel<<<1024, 256, 0, stream>>>(EO, W1p, cvec, V, bv, out_w);
  softmax_kernel<<<NB, 256, 0, stream>>>(out_w);
  context_kernel<<<dim3(NB, 8), 256, 0, stream>>>(EO, out_w, out_ctx);
}